// Round 6
// baseline (1160.375 us; speedup 1.0000x reference)
//
#include <hip/hip_runtime.h>
#include <hip/hip_fp16.h>
#include <math.h>

#define NN 50000
#define NE 1600000
#define H  32
#define ED 16
#define FIN 23
#define NL 4
#define CPAD 16     // ints per histogram counter (64B line) to cut atomic line contention
#define LW 19       // LDS row words: 16 half2-packed m + 3 fp32 coord

union F4 { float4 v; float f[4]; };

__device__ __forceinline__ float silu_f(float v) {
    float e = __expf(-v);
    return v * __builtin_amdgcn_rcpf(1.0f + e);
}

// hid += (4 rows of W) dot (4 input vals in hv4); W rows wave-uniform -> s_load + v_fmac
__device__ __forceinline__ void acc4(float hid[H], float4 hv4, const float* __restrict__ w) {
    F4 u; u.v = hv4;
    #pragma unroll
    for (int jj = 0; jj < 4; ++jj) {
        float v = u.f[jj];
        #pragma unroll
        for (int k = 0; k < H; ++k) hid[k] = fmaf(v, w[jj * H + k], hid[k]);
    }
}

// ---------------- per-layer weight pre-products: W2X = W2@XW1, cvec = b2@XW1+xb1 ----

__global__ __launch_bounds__(256) void k_prep(
    const float* __restrict__ pe_w2, const float* __restrict__ pe_b2,
    const float* __restrict__ px_w1, const float* __restrict__ px_b1,
    float* __restrict__ w2x, float* __restrict__ cvec)
{
    int l = blockIdx.x;
    const float* w2  = pe_w2 + (size_t)l * H * H;
    const float* xw1 = px_w1 + (size_t)l * H * H;
    int tid = threadIdx.x;
    #pragma unroll
    for (int q = 0; q < 4; ++q) {
        int idx = q * 256 + tid;          // 0..1023 = j*32+k
        int j = idx >> 5, k = idx & 31;
        float acc = 0.0f;
        #pragma unroll
        for (int t = 0; t < H; ++t) acc = fmaf(w2[j * H + t], xw1[t * H + k], acc);
        w2x[(size_t)l * H * H + idx] = acc;
    }
    if (tid < H) {
        const float* b2 = pe_b2 + l * H;
        float acc = px_b1[l * H + tid];
        #pragma unroll
        for (int t = 0; t < H; ++t) acc = fmaf(b2[t], xw1[t * H + tid], acc);
        cvec[l * H + tid] = acc;
    }
}

// ---------------- CSR build (once per call) ----------------

__global__ __launch_bounds__(256) void k_hist(
    const int* __restrict__ edst, int* __restrict__ cnt, int* __restrict__ rank)
{
    int e = blockIdx.x * 256 + threadIdx.x;
    if (e >= NE) return;
    rank[e] = atomicAdd(&cnt[(size_t)edst[e] * CPAD], 1);
}

__global__ __launch_bounds__(1024) void k_scan(
    const int* __restrict__ cnt, int* __restrict__ rs)
{
    __shared__ int wsum[16];
    __shared__ int s_carry;
    int t = threadIdx.x;
    int lane = t & 63, wid = t >> 6;
    if (t == 0) s_carry = 0;
    __syncthreads();
    for (int base = 0; base < NN; base += 1024) {
        int i = base + t;
        int v = (i < NN) ? cnt[(size_t)i * CPAD] : 0;
        int incl = v;
        #pragma unroll
        for (int off = 1; off < 64; off <<= 1) {
            int u = __shfl_up(incl, off, 64);
            if (lane >= off) incl += u;
        }
        if (lane == 63) wsum[wid] = incl;
        __syncthreads();
        int wpre = 0;
        #pragma unroll
        for (int w = 0; w < 16; ++w) { int ws = wsum[w]; wpre += (w < wid) ? ws : 0; }
        int carry = s_carry;
        if (i < NN) rs[i] = carry + wpre + incl - v;   // exclusive
        __syncthreads();
        if (t == 1023) s_carry = carry + wpre + incl;
        __syncthreads();
    }
    if (t == 0) rs[NN] = s_carry;
}

// fused scatter+permute: place edge e's attrs + packed (src,dst) directly at its slot
__global__ __launch_bounds__(256) void k_scatter2(
    const int* __restrict__ esrc, const int* __restrict__ edst,
    const int* __restrict__ rank, const int* __restrict__ rs,
    const float* __restrict__ ea,
    float* __restrict__ ea_s, unsigned int* __restrict__ sdp)
{
    int e = blockIdx.x * 256 + threadIdx.x;
    if (e >= NE) return;
    int s = esrc[e], d = edst[e];
    int slot = rs[d] + rank[e];
    const float4* src4 = (const float4*)(ea + (size_t)e * ED);   // coalesced read
    float4* dst4 = (float4*)(ea_s + (size_t)slot * ED);          // random 64B write
    #pragma unroll
    for (int j = 0; j < ED / 4; ++j) dst4[j] = src4[j];
    sdp[slot] = (unsigned int)s | ((unsigned int)d << 16);       // both < 2^16
}

// ---------------- input projection + x padding + layer-0 node pre-projections -----

__global__ __launch_bounds__(256) void proj2(
    const float* __restrict__ feat, const float* __restrict__ pos,
    const float* __restrict__ W, const float* __restrict__ bias,
    const float* __restrict__ pew1,
    float* __restrict__ h, float* __restrict__ a, float* __restrict__ b,
    float4* __restrict__ xp)
{
    int n = blockIdx.x * 256 + threadIdx.x;
    if (n >= NN) return;
    float acc[H];
    #pragma unroll
    for (int k = 0; k < H; ++k) acc[k] = bias[k];
    #pragma unroll 1
    for (int j = 0; j < FIN; ++j) {
        float v = feat[n * FIN + j];
        const float* w = W + j * H;
        #pragma unroll
        for (int k = 0; k < H; ++k) acc[k] = fmaf(v, w[k], acc[k]);
    }
    float4* h4 = (float4*)(h + (size_t)n * H);
    #pragma unroll
    for (int k4 = 0; k4 < H / 4; ++k4) {
        float4 o;
        o.x = acc[4*k4+0]; o.y = acc[4*k4+1]; o.z = acc[4*k4+2]; o.w = acc[4*k4+3];
        h4[k4] = o;
    }
    float pa[H];
    #pragma unroll
    for (int k = 0; k < H; ++k) pa[k] = 0.0f;
    #pragma unroll 1
    for (int j = 0; j < H; ++j) {
        float v = acc[j];
        const float* w = pew1 + j * H;
        #pragma unroll
        for (int k = 0; k < H; ++k) pa[k] = fmaf(v, w[k], pa[k]);
    }
    float4* a4 = (float4*)(a + (size_t)n * H);
    #pragma unroll
    for (int k4 = 0; k4 < H / 4; ++k4) {
        float4 o;
        o.x = pa[4*k4+0]; o.y = pa[4*k4+1]; o.z = pa[4*k4+2]; o.w = pa[4*k4+3];
        a4[k4] = o;
    }
    #pragma unroll
    for (int k = 0; k < H; ++k) pa[k] = 0.0f;
    #pragma unroll 1
    for (int j = 0; j < H; ++j) {
        float v = acc[j];
        const float* w = pew1 + (H + j) * H;
        #pragma unroll
        for (int k = 0; k < H; ++k) pa[k] = fmaf(v, w[k], pa[k]);
    }
    float4* b4 = (float4*)(b + (size_t)n * H);
    #pragma unroll
    for (int k4 = 0; k4 < H / 4; ++k4) {
        float4 o;
        o.x = pa[4*k4+0]; o.y = pa[4*k4+1]; o.z = pa[4*k4+2]; o.w = pa[4*k4+3];
        b4[k4] = o;
    }
    float4 xo;
    xo.x = pos[3*n+0]; xo.y = pos[3*n+1]; xo.z = pos[3*n+2]; xo.w = 0.0f;
    xp[n] = xo;
}

// ---------------- edge kernel: fp16-packed LDS seg-reduce ----------------

__global__ __launch_bounds__(256) void egnn_edge5(
    const float* __restrict__ a, const float* __restrict__ b,
    const float4* __restrict__ xp,
    const float* __restrict__ ea_s, const unsigned int* __restrict__ sdp,
    const float* __restrict__ w1, const float* __restrict__ b1,
    const float* __restrict__ w2x, const float* __restrict__ cvec,
    const float* __restrict__ xw2, const float* __restrict__ xb2,
    float* __restrict__ agg, float* __restrict__ dxb)
{
    __shared__ unsigned int ldsu[256 * LW];
    __shared__ int s_start[4][66];
    __shared__ int s_dstv[4][64];
    __shared__ int s_nseg[4];

    int tid = threadIdx.x;
    int w = tid >> 6, lane = tid & 63;
    int slot = blockIdx.x * 256 + tid;          // grid exact: NE = 6250*256

    unsigned int sd = sdp[slot];
    int s = (int)(sd & 0xffffu), d = (int)(sd >> 16);

    // hid = b1 + a[src] + b[dst]
    float hid[H];
    const float4* av = (const float4*)(a + (size_t)s * H);
    const float4* bv = (const float4*)(b + (size_t)d * H);
    #pragma unroll
    for (int k4 = 0; k4 < H / 4; ++k4) {
        F4 ua, ub; ua.v = av[k4]; ub.v = bv[k4];
        #pragma unroll
        for (int jj = 0; jj < 4; ++jj)
            hid[4*k4+jj] = b1[4*k4+jj] + ua.f[jj] + ub.f[jj];
    }

    // + ea_s @ W1[rows 64..79]
    const float4* eav = (const float4*)(ea_s + (size_t)slot * ED);
    #pragma unroll 1
    for (int j4 = 0; j4 < ED / 4; ++j4)
        acc4(hid, eav[j4], w1 + (2 * H + j4 * 4) * H);

    // + dist * W1[row 80]
    float4 xi = xp[s];
    float4 xj = xp[d];
    float d0 = xj.x - xi.x, d1 = xj.y - xi.y, d2 = xj.z - xi.z;
    float sq = d0*d0 + d1*d1 + d2*d2;
    float dist = __builtin_amdgcn_sqrtf(sq + 1e-9f);
    {
        const float* wl = w1 + (2 * H + ED) * H;
        #pragma unroll
        for (int k = 0; k < H; ++k) hid[k] = fmaf(dist, wl[k], hid[k]);
    }

    // s = silu(hid); gh = cvec + s @ W2X
    float sarr[H];
    float gh[H];
    #pragma unroll
    for (int k = 0; k < H; ++k) gh[k] = cvec[k];
    #pragma unroll
    for (int j = 0; j < H; ++j) {
        float v = silu_f(hid[j]);
        sarr[j] = v;
        const float* ww = w2x + j * H;
        #pragma unroll
        for (int k = 0; k < H; ++k) gh[k] = fmaf(v, ww[k], gh[k]);
    }

    float gate = xb2[0];
    #pragma unroll
    for (int j = 0; j < H; ++j) gate = fmaf(silu_f(gh[j]), xw2[j], gate);
    float scale = gate * __builtin_amdgcn_rcpf(__builtin_amdgcn_sqrtf(sq) + 1e-9f);

    // stash row: 16 half2 words (m) + 3 fp32 words (coord)
    unsigned int* row = &ldsu[tid * LW];
    #pragma unroll
    for (int k2 = 0; k2 < 16; ++k2) {
        __half2 hh = __floats2half2_rn(sarr[2*k2], sarr[2*k2+1]);
        row[k2] = *reinterpret_cast<unsigned int*>(&hh);
    }
    row[16] = __float_as_uint(d0 * scale);
    row[17] = __float_as_uint(d1 * scale);
    row[18] = __float_as_uint(d2 * scale);

    // segment boundaries within this wave (dst sorted over slots)
    int dprev = __shfl_up(d, 1, 64);
    bool flag = (lane == 0) || (d != dprev);
    unsigned long long ball = __ballot(flag);
    unsigned long long mask_le = (lane == 63) ? ~0ull : ((1ull << (lane + 1)) - 1ull);
    int segid = __popcll(ball & mask_le) - 1;
    if (flag) { s_start[w][segid] = lane; s_dstv[w][segid] = d; }
    if (lane == 0) {
        int ns = __popcll(ball);
        s_start[w][ns] = 64;
        s_nseg[w] = ns;
    }
    __syncthreads();

    // segment sums -> row atomics
    int nseg = s_nseg[w];
    const unsigned int* wrows = &ldsu[(w * 64) * LW];
    int sub = lane >> 5, col = lane & 31;
    int word = col >> 1, sh = (col & 1) * 16;
    #pragma unroll 1
    for (int sg = sub; sg < nseg; sg += 2) {
        int r0 = s_start[w][sg], r1 = s_start[w][sg + 1];
        float v = 0.0f;
        #pragma unroll 1
        for (int r = r0; r < r1; ++r) {
            unsigned int u = wrows[r * LW + word];
            v += __half2float(__ushort_as_half((unsigned short)(u >> sh)));
        }
        unsafeAtomicAdd(&agg[(size_t)s_dstv[w][sg] * H + col], v);
    }
    #pragma unroll 1
    for (int j = lane; j < nseg * 4; j += 64) {
        int sg = j >> 2, c = j & 3;
        if (c < 3) {
            int r0 = s_start[w][sg], r1 = s_start[w][sg + 1];
            float v = 0.0f;
            #pragma unroll 1
            for (int r = r0; r < r1; ++r) v += __uint_as_float(wrows[r * LW + 16 + c]);
            unsafeAtomicAdd(&dxb[(size_t)s_dstv[w][sg] * 4 + c], v);
        }
    }
}

// ---------------- node kernel: finish agg, phi_h, LN, x, next a/b ----------------

__global__ __launch_bounds__(256) void egnn_node5(
    const float* __restrict__ h, const float* __restrict__ agg,
    const float4* __restrict__ xin, const float* __restrict__ dxb,
    const int* __restrict__ rs,
    const float* __restrict__ ew2, const float* __restrict__ eb2,
    const float* __restrict__ w1, const float* __restrict__ b1,
    const float* __restrict__ w2, const float* __restrict__ b2,
    const float* __restrict__ lng, const float* __restrict__ lnb,
    const float* __restrict__ nxtw1, int last,
    float* __restrict__ hout, float* __restrict__ xout,
    float* __restrict__ aout, float* __restrict__ bout)
{
    int n = blockIdx.x * 256 + threadIdx.x;
    if (n >= NN) return;
    const float4* h4 = (const float4*)(h + (size_t)n * H);
    const float4* a4 = (const float4*)(agg + (size_t)n * H);

    // ma = deg*b2_e + agg_s @ W2_e
    float degf = (float)(rs[n + 1] - rs[n]);
    float ma[H];
    #pragma unroll
    for (int k = 0; k < H; ++k) ma[k] = degf * eb2[k];
    #pragma unroll 1
    for (int j4 = 0; j4 < H / 4; ++j4)
        acc4(ma, a4[j4], ew2 + (j4 * 4) * H);

    float hv[H];
    float hid[H];
    #pragma unroll
    for (int k = 0; k < H; ++k) hid[k] = b1[k];
    #pragma unroll 1
    for (int j4 = 0; j4 < H / 4; ++j4) {
        F4 u; u.v = h4[j4];
        #pragma unroll
        for (int jj = 0; jj < 4; ++jj) hv[4*j4+jj] = u.f[jj];
        acc4(hid, u.v, w1 + (j4 * 4) * H);
    }
    #pragma unroll
    for (int j = 0; j < H; ++j) {
        float v = ma[j];
        const float* ww = w1 + (H + j) * H;
        #pragma unroll
        for (int k = 0; k < H; ++k) hid[k] = fmaf(v, ww[k], hid[k]);
    }

    float dh[H];
    #pragma unroll
    for (int k = 0; k < H; ++k) dh[k] = b2[k];
    #pragma unroll
    for (int j = 0; j < H; ++j) {
        float v = silu_f(hid[j]);
        const float* ww = w2 + j * H;
        #pragma unroll
        for (int k = 0; k < H; ++k) dh[k] = fmaf(v, ww[k], dh[k]);
    }

    float y[H];
    float mu = 0.0f;
    #pragma unroll
    for (int k = 0; k < H; ++k) { y[k] = hv[k] + dh[k]; mu += y[k]; }
    mu *= (1.0f / H);
    float var = 0.0f;
    #pragma unroll
    for (int k = 0; k < H; ++k) { float t = y[k] - mu; var += t * t; }
    var *= (1.0f / H);
    float rstd = rsqrtf(var + 1e-5f);

    float hn[H];
    #pragma unroll
    for (int k = 0; k < H; ++k) hn[k] = (y[k] - mu) * rstd * lng[k] + lnb[k];

    float4* ho4 = (float4*)(hout + (size_t)n * H);
    #pragma unroll
    for (int k4 = 0; k4 < H / 4; ++k4) {
        float4 o;
        o.x = hn[4*k4+0]; o.y = hn[4*k4+1]; o.z = hn[4*k4+2]; o.w = hn[4*k4+3];
        ho4[k4] = o;
    }

    float4 xi = xin[n];
    float nx0 = xi.x + dxb[(size_t)n * 4 + 0];
    float nx1 = xi.y + dxb[(size_t)n * 4 + 1];
    float nx2 = xi.z + dxb[(size_t)n * 4 + 2];
    if (last) {
        xout[3*n+0] = nx0; xout[3*n+1] = nx1; xout[3*n+2] = nx2;
    } else {
        float4 o; o.x = nx0; o.y = nx1; o.z = nx2; o.w = 0.0f;
        ((float4*)xout)[n] = o;
    }

    if (!last) {
        float pa[H];
        #pragma unroll
        for (int k = 0; k < H; ++k) pa[k] = 0.0f;
        #pragma unroll 1
        for (int j = 0; j < H; ++j) {
            float v = hn[j];
            const float* ww = nxtw1 + j * H;
            #pragma unroll
            for (int k = 0; k < H; ++k) pa[k] = fmaf(v, ww[k], pa[k]);
        }
        float4* ao4 = (float4*)(aout + (size_t)n * H);
        #pragma unroll
        for (int k4 = 0; k4 < H / 4; ++k4) {
            float4 o;
            o.x = pa[4*k4+0]; o.y = pa[4*k4+1]; o.z = pa[4*k4+2]; o.w = pa[4*k4+3];
            ao4[k4] = o;
        }
        #pragma unroll
        for (int k = 0; k < H; ++k) pa[k] = 0.0f;
        #pragma unroll 1
        for (int j = 0; j < H; ++j) {
            float v = hn[j];
            const float* ww = nxtw1 + (H + j) * H;
            #pragma unroll
            for (int k = 0; k < H; ++k) pa[k] = fmaf(v, ww[k], pa[k]);
        }
        float4* bo4 = (float4*)(bout + (size_t)n * H);
        #pragma unroll
        for (int k4 = 0; k4 < H / 4; ++k4) {
            float4 o;
            o.x = pa[4*k4+0]; o.y = pa[4*k4+1]; o.z = pa[4*k4+2]; o.w = pa[4*k4+3];
            bo4[k4] = o;
        }
    }
}

extern "C" void kernel_launch(void* const* d_in, const int* in_sizes, int n_in,
                              void* d_out, int out_size, void* d_ws, size_t ws_size,
                              hipStream_t stream) {
    const float* node_pos  = (const float*)d_in[0];
    const float* node_feat = (const float*)d_in[1];
    const float* edge_attr = (const float*)d_in[2];
    const float* proj_w    = (const float*)d_in[3];
    const float* proj_b    = (const float*)d_in[4];
    const float* pe_w1     = (const float*)d_in[5];
    const float* pe_b1     = (const float*)d_in[6];
    const float* pe_w2     = (const float*)d_in[7];
    const float* pe_b2     = (const float*)d_in[8];
    const float* ph_w1     = (const float*)d_in[9];
    const float* ph_b1     = (const float*)d_in[10];
    const float* ph_w2     = (const float*)d_in[11];
    const float* ph_b2     = (const float*)d_in[12];
    const float* px_w1     = (const float*)d_in[13];
    const float* px_b1     = (const float*)d_in[14];
    const float* px_w2     = (const float*)d_in[15];
    const float* px_b2     = (const float*)d_in[16];
    const float* ln_g      = (const float*)d_in[17];
    const float* ln_b      = (const float*)d_in[18];
    const int*   eidx      = (const int*)d_in[19];
    const int*   esrc      = eidx;
    const int*   edst      = eidx + NE;

    float* out_h = (float*)d_out;
    float* out_x = out_h + (size_t)NN * H;

    // ---- workspace layout (offsets in floats; all 16B aligned) ----
    size_t off = 0;
    float* ea_s = (float*)d_ws;                off += (size_t)NE * ED;      // 102.4 MB
    unsigned int* sdp = (unsigned int*)((float*)d_ws + off); off += NE;     // 6.4 MB
    float* abuf = (float*)d_ws + off;          off += (size_t)NN * H;
    float* bbuf = (float*)d_ws + off;          off += (size_t)NN * H;
    float* h_a  = (float*)d_ws + off;          off += (size_t)NN * H;
    float* h_b  = (float*)d_ws + off;          off += (size_t)NN * H;
    float4* xp_a = (float4*)((float*)d_ws + off); off += (size_t)NN * 4;
    float4* xp_b = (float4*)((float*)d_ws + off); off += (size_t)NN * 4;
    float* agg  = (float*)d_ws + off;          off += (size_t)NN * H;       // zeroed per layer
    float* dxb  = (float*)d_ws + off;          off += (size_t)NN * 4;       // adjacent to agg
    float* w2x  = (float*)d_ws + off;          off += (size_t)NL * H * H;
    float* cvec = (float*)d_ws + off;          off += (size_t)NL * H;
    int*   cnt  = (int*)((float*)d_ws + off);  off += (size_t)NN * CPAD;
    int*   rs   = (int*)((float*)d_ws + off);  off += NN + 4;
    int*   rank = (int*)((float*)d_ws + off);  off += NE;

    dim3 nblk((NN + 255) / 256), eblk(NE / 256);   // NE = 6250*256 exactly

    hipMemsetAsync(cnt, 0, (size_t)NN * CPAD * sizeof(int), stream);
    k_hist<<<eblk, 256, 0, stream>>>(edst, cnt, rank);
    k_scan<<<1, 1024, 0, stream>>>(cnt, rs);
    k_scatter2<<<eblk, 256, 0, stream>>>(esrc, edst, rank, rs, edge_attr, ea_s, sdp);
    k_prep<<<dim3(NL), 256, 0, stream>>>(pe_w2, pe_b2, px_w1, px_b1, w2x, cvec);

    proj2<<<nblk, 256, 0, stream>>>(node_feat, node_pos, proj_w, proj_b, pe_w1,
                                    h_a, abuf, bbuf, xp_a);

    const float* hcur = h_a;
    const float4* xcur = xp_a;
    float* hbufs[2] = { h_b, h_a };
    float4* xbufs[2] = { xp_b, xp_a };

    for (int l = 0; l < NL; ++l) {
        hipMemsetAsync(agg, 0, (size_t)NN * (H + 4) * sizeof(float), stream);
        egnn_edge5<<<eblk, 256, 0, stream>>>(abuf, bbuf, xcur, ea_s, sdp,
            pe_w1 + (size_t)l * (2*H + ED + 1) * H, pe_b1 + l * H,
            w2x + (size_t)l * H * H,               cvec + l * H,
            px_w2 + (size_t)l * H,                 px_b2 + l,
            agg, dxb);
        int last = (l == NL - 1);
        float* ho = last ? out_h : hbufs[l & 1];
        float* xo = last ? out_x : (float*)xbufs[l & 1];
        const float* nxtw1 = last ? pe_w1 : (pe_w1 + (size_t)(l + 1) * (2*H + ED + 1) * H);
        egnn_node5<<<nblk, 256, 0, stream>>>(hcur, agg, xcur, dxb, rs,
            pe_w2 + (size_t)l * H * H, pe_b2 + l * H,
            ph_w1 + (size_t)l * 2 * H * H, ph_b1 + l * H,
            ph_w2 + (size_t)l * H * H,     ph_b2 + l * H,
            ln_g + l * H, ln_b + l * H,
            nxtw1, last, ho, xo, abuf, bbuf);
        hcur = ho;
        xcur = xbufs[l & 1];
    }
}

// Round 11
// 1005.334 us; speedup vs baseline: 1.1542x; 1.1542x over previous
//
#include <hip/hip_runtime.h>
#include <hip/hip_fp16.h>
#include <math.h>

#define NN 50000
#define NE 1600000
#define H  32
#define ED 16
#define FIN 23
#define NL 4
#define W1ROWS 81   // 2H+ED+1
#define CPAD 16     // ints per histogram counter (64B line)
#define LW 19       // LDS row words: 16 half2-packed m + 3 fp32 coord

typedef _Float16 hv2 __attribute__((ext_vector_type(2)));
typedef __fp16   fv2 __attribute__((ext_vector_type(2)));
union H2U { unsigned int u; hv2 h; fv2 f; };
union F4 { float4 v; float f[4]; };

__device__ __forceinline__ unsigned int pack2(float a, float b) {
    H2U r; r.f = __builtin_amdgcn_cvt_pkrtz(a, b);
    return r.u;
}

__device__ __forceinline__ float fdot2f(unsigned int a, unsigned int b, float c) {
    H2U ua, ub; ua.u = a; ub.u = b;
    return __builtin_amdgcn_fdot2(ua.h, ub.h, c, false);
}

__device__ __forceinline__ float silu_f(float v) {
    float e = __expf(-v);
    return v * __builtin_amdgcn_rcpf(1.0f + e);
}

// hid += (4 rows of W) dot (4 vals); W rows wave-uniform -> s_load + v_fmac
__device__ __forceinline__ void acc4(float hid[H], float4 hv4, const float* __restrict__ w) {
    F4 u; u.v = hv4;
    #pragma unroll
    for (int jj = 0; jj < 4; ++jj) {
        float v = u.f[jj];
        #pragma unroll
        for (int k = 0; k < H; ++k) hid[k] = fmaf(v, w[jj * H + k], hid[k]);
    }
}

// ---------------- per-layer weight prep: fp16-packed W1e, W2X=W2@XW1, cvec -------

__global__ __launch_bounds__(256) void k_prep(
    const float* __restrict__ pe_w1, const float* __restrict__ pe_w2,
    const float* __restrict__ pe_b2,
    const float* __restrict__ px_w1, const float* __restrict__ px_b1,
    unsigned int* __restrict__ w1h, unsigned int* __restrict__ w2xh,
    float* __restrict__ cvec)
{
    __shared__ float w2x[H * H];
    int l = blockIdx.x;
    const float* w2  = pe_w2 + (size_t)l * H * H;
    const float* xw1 = px_w1 + (size_t)l * H * H;
    int tid = threadIdx.x;
    #pragma unroll
    for (int q = 0; q < 4; ++q) {
        int idx = q * 256 + tid;          // j*32+k
        int j = idx >> 5, k = idx & 31;
        float acc = 0.0f;
        #pragma unroll
        for (int t = 0; t < H; ++t) acc = fmaf(w2[j * H + t], xw1[t * H + k], acc);
        w2x[idx] = acc;
    }
    __syncthreads();
    #pragma unroll
    for (int q = 0; q < 2; ++q) {
        int i2 = q * 256 + tid;           // j2*32+k, j2 in [0,16)
        int j2 = i2 >> 5, k = i2 & 31;
        w2xh[(size_t)l * 512 + i2] = pack2(w2x[(2*j2) * H + k], w2x[(2*j2+1) * H + k]);
    }
    {
        int j2 = tid >> 5, k = tid & 31;  // j2 in [0,8)
        const float* w1 = pe_w1 + (size_t)l * W1ROWS * H;
        w1h[(size_t)l * 256 + tid] = pack2(w1[(2*H + 2*j2) * H + k], w1[(2*H + 2*j2+1) * H + k]);
    }
    if (tid < H) {
        float acc = px_b1[l * H + tid];
        const float* b2 = pe_b2 + l * H;
        #pragma unroll
        for (int t = 0; t < H; ++t) acc = fmaf(b2[t], xw1[t * H + tid], acc);
        cvec[l * H + tid] = acc;
    }
}

// ---------------- CSR build (once per call) ----------------

__global__ __launch_bounds__(256) void k_hist(
    const int* __restrict__ edst, int* __restrict__ cnt, int* __restrict__ rank)
{
    int e = blockIdx.x * 256 + threadIdx.x;
    if (e >= NE) return;
    rank[e] = atomicAdd(&cnt[(size_t)edst[e] * CPAD], 1);
}

__global__ __launch_bounds__(1024) void k_scan(
    const int* __restrict__ cnt, int* __restrict__ rs)
{
    __shared__ int wsum[16];
    __shared__ int s_carry;
    int t = threadIdx.x;
    int lane = t & 63, wid = t >> 6;
    if (t == 0) s_carry = 0;
    __syncthreads();
    for (int base = 0; base < NN; base += 1024) {
        int i = base + t;
        int v = (i < NN) ? cnt[(size_t)i * CPAD] : 0;
        int incl = v;
        #pragma unroll
        for (int off = 1; off < 64; off <<= 1) {
            int u = __shfl_up(incl, off, 64);
            if (lane >= off) incl += u;
        }
        if (lane == 63) wsum[wid] = incl;
        __syncthreads();
        int wpre = 0;
        #pragma unroll
        for (int w = 0; w < 16; ++w) { int ws = wsum[w]; wpre += (w < wid) ? ws : 0; }
        int carry = s_carry;
        if (i < NN) rs[i] = carry + wpre + incl - v;   // exclusive
        __syncthreads();
        if (t == 1023) s_carry = carry + wpre + incl;
        __syncthreads();
    }
    if (t == 0) rs[NN] = s_carry;
}

// fused scatter+permute: fp16-convert edge_attr + pack (src,dst) at slot
__global__ __launch_bounds__(256) void k_scatter2(
    const int* __restrict__ esrc, const int* __restrict__ edst,
    const int* __restrict__ rank, const int* __restrict__ rs,
    const float* __restrict__ ea,
    unsigned int* __restrict__ ea_h, unsigned int* __restrict__ sdp)
{
    int e = blockIdx.x * 256 + threadIdx.x;
    if (e >= NE) return;
    int s = esrc[e], d = edst[e];
    int slot = rs[d] + rank[e];
    const float4* src4 = (const float4*)(ea + (size_t)e * ED);   // coalesced read
    uint2* dst2 = (uint2*)(ea_h + (size_t)slot * 8);             // random 32B write
    #pragma unroll
    for (int j = 0; j < ED / 4; ++j) {
        float4 v = src4[j];
        uint2 o; o.x = pack2(v.x, v.y); o.y = pack2(v.z, v.w);
        dst2[j] = o;
    }
    sdp[slot] = (unsigned int)s | ((unsigned int)d << 16);       // both < 2^16
}

// ---------------- input projection + x padding + layer-0 a/b ----------------

__global__ __launch_bounds__(256) void proj2(
    const float* __restrict__ feat, const float* __restrict__ pos,
    const float* __restrict__ W, const float* __restrict__ bias,
    const float* __restrict__ pew1,
    float* __restrict__ h, float* __restrict__ a, float* __restrict__ b,
    float4* __restrict__ xp)
{
    int n = blockIdx.x * 256 + threadIdx.x;
    if (n >= NN) return;
    float acc[H];
    #pragma unroll
    for (int k = 0; k < H; ++k) acc[k] = bias[k];
    #pragma unroll 1
    for (int j = 0; j < FIN; ++j) {
        float v = feat[n * FIN + j];
        const float* w = W + j * H;
        #pragma unroll
        for (int k = 0; k < H; ++k) acc[k] = fmaf(v, w[k], acc[k]);
    }
    float4* h4 = (float4*)(h + (size_t)n * H);
    #pragma unroll
    for (int k4 = 0; k4 < H / 4; ++k4) {
        float4 o;
        o.x = acc[4*k4+0]; o.y = acc[4*k4+1]; o.z = acc[4*k4+2]; o.w = acc[4*k4+3];
        h4[k4] = o;
    }
    float pa[H];
    #pragma unroll
    for (int k = 0; k < H; ++k) pa[k] = 0.0f;
    #pragma unroll 1
    for (int j = 0; j < H; ++j) {
        float v = acc[j];
        const float* w = pew1 + j * H;
        #pragma unroll
        for (int k = 0; k < H; ++k) pa[k] = fmaf(v, w[k], pa[k]);
    }
    float4* a4 = (float4*)(a + (size_t)n * H);
    #pragma unroll
    for (int k4 = 0; k4 < H / 4; ++k4) {
        float4 o;
        o.x = pa[4*k4+0]; o.y = pa[4*k4+1]; o.z = pa[4*k4+2]; o.w = pa[4*k4+3];
        a4[k4] = o;
    }
    #pragma unroll
    for (int k = 0; k < H; ++k) pa[k] = 0.0f;
    #pragma unroll 1
    for (int j = 0; j < H; ++j) {
        float v = acc[j];
        const float* w = pew1 + (H + j) * H;
        #pragma unroll
        for (int k = 0; k < H; ++k) pa[k] = fmaf(v, w[k], pa[k]);
    }
    float4* b4 = (float4*)(b + (size_t)n * H);
    #pragma unroll
    for (int k4 = 0; k4 < H / 4; ++k4) {
        float4 o;
        o.x = pa[4*k4+0]; o.y = pa[4*k4+1]; o.z = pa[4*k4+2]; o.w = pa[4*k4+3];
        b4[k4] = o;
    }
    float4 xo;
    xo.x = pos[3*n+0]; xo.y = pos[3*n+1]; xo.z = pos[3*n+2]; xo.w = 0.0f;
    xp[n] = xo;
}

// ---------------- edge kernel: fdot2 GEMMs + barrier-free cooperative seg-reduce --

__global__ __launch_bounds__(256) void egnn_edge6(
    const float* __restrict__ a, const float* __restrict__ b,
    const float4* __restrict__ xp,
    const unsigned int* __restrict__ ea_h, const unsigned int* __restrict__ sdp,
    const unsigned int* __restrict__ w1h, const float* __restrict__ b1,
    const float* __restrict__ w1,          // fp32 layer W1 (for dist row 80)
    const unsigned int* __restrict__ w2xh, const float* __restrict__ cvec,
    const float* __restrict__ xw2, const float* __restrict__ xb2,
    float* __restrict__ agg, float* __restrict__ dxb)
{
    __shared__ unsigned int ldsu[256 * LW + 4];   // +4: c==3 dummy-read pad

    int tid = threadIdx.x;
    int w = tid >> 6, lane = tid & 63;
    int slot = blockIdx.x * 256 + tid;            // grid exact: NE = 6250*256

    unsigned int sd = sdp[slot];
    int s = (int)(sd & 0xffffu), d = (int)(sd >> 16);

    // hid = b1 + a[src] + b[dst]   (fp32)
    float hid[H];
    const float4* av = (const float4*)(a + (size_t)s * H);
    const float4* bv = (const float4*)(b + (size_t)d * H);
    #pragma unroll
    for (int k4 = 0; k4 < H / 4; ++k4) {
        F4 ua, ub; ua.v = av[k4]; ub.v = bv[k4];
        #pragma unroll
        for (int jj = 0; jj < 4; ++jj)
            hid[4*k4+jj] = b1[4*k4+jj] + ua.f[jj] + ub.f[jj];
    }

    // + ea(fp16) @ W1e(fp16) via dot2
    const uint4* ev = (const uint4*)(ea_h + (size_t)slot * 8);
    uint4 e0 = ev[0], e1 = ev[1];
    unsigned int ew[8] = { e0.x, e0.y, e0.z, e0.w, e1.x, e1.y, e1.z, e1.w };
    #pragma unroll 1
    for (int j2 = 0; j2 < 8; ++j2) {
        unsigned int ea2 = ew[j2];
        const unsigned int* wr = w1h + j2 * H;
        #pragma unroll
        for (int k = 0; k < H; ++k) hid[k] = fdot2f(ea2, wr[k], hid[k]);
    }

    // + dist * W1[row 80] (fp32)
    float4 xi = xp[s];
    float4 xj = xp[d];
    float d0 = xj.x - xi.x, d1 = xj.y - xi.y, d2 = xj.z - xi.z;
    float sq = d0*d0 + d1*d1 + d2*d2;
    float dist = __builtin_amdgcn_sqrtf(sq + 1e-9f);
    {
        const float* wl = w1 + (2 * H + ED) * H;
        #pragma unroll
        for (int k = 0; k < H; ++k) hid[k] = fmaf(dist, wl[k], hid[k]);
    }

    // s = silu(hid) packed fp16 pairs (reused for GEMM2 AND the LDS row)
    unsigned int sp[16];
    #pragma unroll
    for (int j2 = 0; j2 < 16; ++j2)
        sp[j2] = pack2(silu_f(hid[2*j2]), silu_f(hid[2*j2+1]));

    // gh = cvec + s @ W2X via dot2
    float gh[H];
    #pragma unroll
    for (int k = 0; k < H; ++k) gh[k] = cvec[k];
    #pragma unroll 1
    for (int j2 = 0; j2 < 16; ++j2) {
        unsigned int sv = sp[j2];
        const unsigned int* wr = w2xh + j2 * H;
        #pragma unroll
        for (int k = 0; k < H; ++k) gh[k] = fdot2f(sv, wr[k], gh[k]);
    }

    float gate = xb2[0];
    #pragma unroll
    for (int j = 0; j < H; ++j) gate = fmaf(silu_f(gh[j]), xw2[j], gate);
    float scale = gate * __builtin_amdgcn_rcpf(__builtin_amdgcn_sqrtf(sq) + 1e-9f);

    // stash row: 16 packed m words + 3 fp32 coord words
    unsigned int* row = &ldsu[tid * LW];
    #pragma unroll
    for (int k2 = 0; k2 < 16; ++k2) row[k2] = sp[k2];
    row[16] = __float_as_uint(d0 * scale);
    row[17] = __float_as_uint(d1 * scale);
    row[18] = __float_as_uint(d2 * scale);

    // wave-local segments (dst-sorted slots); NO __syncthreads needed:
    // each wave reads only its own 64 LDS rows.
    int dprev = __shfl_up(d, 1, 64);
    bool flag = (lane == 0) || (d != dprev);
    unsigned long long ball = __ballot(flag);

    int half = lane >> 5, col = lane & 31;
    int word = col >> 1, sh = (col & 1) * 16;
    int c = lane & 3, strip = lane >> 2;
    const unsigned int* wrows = &ldsu[(w * 64) * LW];

    unsigned long long cur = ball;
    while (cur) {
        int r0 = (int)__builtin_ctzll(cur);
        unsigned long long nxt = cur & (cur - 1);
        int r1 = nxt ? (int)__builtin_ctzll(nxt) : 64;
        int dseg = __shfl(d, r0, 64);

        // m columns: 64 lanes = 32 cols x 2 row-strips
        float v = 0.0f;
        #pragma unroll 1
        for (int r = r0 + half; r < r1; r += 2) {
            unsigned int u = wrows[r * LW + word];
            v += __half2float(__ushort_as_half((unsigned short)(u >> sh)));
        }
        v += __shfl_xor(v, 32, 64);
        if (lane < 32) unsafeAtomicAdd(&agg[(size_t)dseg * H + col], v);

        // coord columns: 4 "cols" (3 real) x 16 row-strips
        float cv = 0.0f;
        #pragma unroll 1
        for (int r = r0 + strip; r < r1; r += 16)
            cv += __uint_as_float(wrows[r * LW + 16 + c]);
        cv += __shfl_xor(cv, 4, 64);
        cv += __shfl_xor(cv, 8, 64);
        cv += __shfl_xor(cv, 16, 64);
        cv += __shfl_xor(cv, 32, 64);
        if (lane < 3) unsafeAtomicAdd(&dxb[(size_t)dseg * 4 + c], cv);

        cur = nxt;
    }
}

// ---------------- node kernel: finish agg, phi_h, LN, x, next a/b; re-zero agg ---

__global__ __launch_bounds__(256) void egnn_node6(
    const float* __restrict__ h, float* __restrict__ agg,
    const float4* __restrict__ xin, float* __restrict__ dxb,
    const int* __restrict__ rs,
    const float* __restrict__ ew2, const float* __restrict__ eb2,
    const float* __restrict__ w1, const float* __restrict__ b1,
    const float* __restrict__ w2, const float* __restrict__ b2,
    const float* __restrict__ lng, const float* __restrict__ lnb,
    const float* __restrict__ nxtw1, int last,
    float* __restrict__ hout, float* __restrict__ xout,
    float* __restrict__ aout, float* __restrict__ bout)
{
    int n = blockIdx.x * 256 + threadIdx.x;
    if (n >= NN) return;
    const float4* h4 = (const float4*)(h + (size_t)n * H);
    float4* a4 = (float4*)(agg + (size_t)n * H);

    // ma = deg*b2_e + agg_s @ W2_e
    float degf = (float)(rs[n + 1] - rs[n]);
    float ma[H];
    #pragma unroll
    for (int k = 0; k < H; ++k) ma[k] = degf * eb2[k];
    #pragma unroll 1
    for (int j4 = 0; j4 < H / 4; ++j4)
        acc4(ma, a4[j4], ew2 + (j4 * 4) * H);

    // re-zero agg for next layer's edge atomics (replaces per-layer memset)
    float4 z; z.x = 0.0f; z.y = 0.0f; z.z = 0.0f; z.w = 0.0f;
    #pragma unroll
    for (int j4 = 0; j4 < H / 4; ++j4) a4[j4] = z;

    float hv[H];
    float hid[H];
    #pragma unroll
    for (int k = 0; k < H; ++k) hid[k] = b1[k];
    #pragma unroll 1
    for (int j4 = 0; j4 < H / 4; ++j4) {
        F4 u; u.v = h4[j4];
        #pragma unroll
        for (int jj = 0; jj < 4; ++jj) hv[4*j4+jj] = u.f[jj];
        acc4(hid, u.v, w1 + (j4 * 4) * H);
    }
    #pragma unroll
    for (int j = 0; j < H; ++j) {
        float v = ma[j];
        const float* ww = w1 + (H + j) * H;
        #pragma unroll
        for (int k = 0; k < H; ++k) hid[k] = fmaf(v, ww[k], hid[k]);
    }

    float dh[H];
    #pragma unroll
    for (int k = 0; k < H; ++k) dh[k] = b2[k];
    #pragma unroll
    for (int j = 0; j < H; ++j) {
        float v = silu_f(hid[j]);
        const float* ww = w2 + j * H;
        #pragma unroll
        for (int k = 0; k < H; ++k) dh[k] = fmaf(v, ww[k], dh[k]);
    }

    float y[H];
    float mu = 0.0f;
    #pragma unroll
    for (int k = 0; k < H; ++k) { y[k] = hv[k] + dh[k]; mu += y[k]; }
    mu *= (1.0f / H);
    float var = 0.0f;
    #pragma unroll
    for (int k = 0; k < H; ++k) { float t = y[k] - mu; var += t * t; }
    var *= (1.0f / H);
    float rstd = rsqrtf(var + 1e-5f);

    float hn[H];
    #pragma unroll
    for (int k = 0; k < H; ++k) hn[k] = (y[k] - mu) * rstd * lng[k] + lnb[k];

    float4* ho4 = (float4*)(hout + (size_t)n * H);
    #pragma unroll
    for (int k4 = 0; k4 < H / 4; ++k4) {
        float4 o;
        o.x = hn[4*k4+0]; o.y = hn[4*k4+1]; o.z = hn[4*k4+2]; o.w = hn[4*k4+3];
        ho4[k4] = o;
    }

    float4 xi = xin[n];
    float nx0 = xi.x + dxb[(size_t)n * 4 + 0];
    float nx1 = xi.y + dxb[(size_t)n * 4 + 1];
    float nx2 = xi.z + dxb[(size_t)n * 4 + 2];
    ((float4*)dxb)[n] = z;   // re-zero for next layer
    if (last) {
        xout[3*n+0] = nx0; xout[3*n+1] = nx1; xout[3*n+2] = nx2;
    } else {
        float4 o; o.x = nx0; o.y = nx1; o.z = nx2; o.w = 0.0f;
        ((float4*)xout)[n] = o;
    }

    if (!last) {
        float pa[H];
        #pragma unroll
        for (int k = 0; k < H; ++k) pa[k] = 0.0f;
        #pragma unroll 1
        for (int j = 0; j < H; ++j) {
            float v = hn[j];
            const float* ww = nxtw1 + j * H;
            #pragma unroll
            for (int k = 0; k < H; ++k) pa[k] = fmaf(v, ww[k], pa[k]);
        }
        float4* ao4 = (float4*)(aout + (size_t)n * H);
        #pragma unroll
        for (int k4 = 0; k4 < H / 4; ++k4) {
            float4 o;
            o.x = pa[4*k4+0]; o.y = pa[4*k4+1]; o.z = pa[4*k4+2]; o.w = pa[4*k4+3];
            ao4[k4] = o;
        }
        #pragma unroll
        for (int k = 0; k < H; ++k) pa[k] = 0.0f;
        #pragma unroll 1
        for (int j = 0; j < H; ++j) {
            float v = hn[j];
            const float* ww = nxtw1 + (H + j) * H;
            #pragma unroll
            for (int k = 0; k < H; ++k) pa[k] = fmaf(v, ww[k], pa[k]);
        }
        float4* bo4 = (float4*)(bout + (size_t)n * H);
        #pragma unroll
        for (int k4 = 0; k4 < H / 4; ++k4) {
            float4 o;
            o.x = pa[4*k4+0]; o.y = pa[4*k4+1]; o.z = pa[4*k4+2]; o.w = pa[4*k4+3];
            bo4[k4] = o;
        }
    }
}

extern "C" void kernel_launch(void* const* d_in, const int* in_sizes, int n_in,
                              void* d_out, int out_size, void* d_ws, size_t ws_size,
                              hipStream_t stream) {
    const float* node_pos  = (const float*)d_in[0];
    const float* node_feat = (const float*)d_in[1];
    const float* edge_attr = (const float*)d_in[2];
    const float* proj_w    = (const float*)d_in[3];
    const float* proj_b    = (const float*)d_in[4];
    const float* pe_w1     = (const float*)d_in[5];
    const float* pe_b1     = (const float*)d_in[6];
    const float* pe_w2     = (const float*)d_in[7];
    const float* pe_b2     = (const float*)d_in[8];
    const float* ph_w1     = (const float*)d_in[9];
    const float* ph_b1     = (const float*)d_in[10];
    const float* ph_w2     = (const float*)d_in[11];
    const float* ph_b2     = (const float*)d_in[12];
    const float* px_w1     = (const float*)d_in[13];
    const float* px_b1     = (const float*)d_in[14];
    const float* px_w2     = (const float*)d_in[15];
    const float* px_b2     = (const float*)d_in[16];
    const float* ln_g      = (const float*)d_in[17];
    const float* ln_b      = (const float*)d_in[18];
    const int*   eidx      = (const int*)d_in[19];
    const int*   esrc      = eidx;
    const int*   edst      = eidx + NE;

    float* out_h = (float*)d_out;
    float* out_x = out_h + (size_t)NN * H;

    // ---- workspace layout (offsets in 4B words; all 16B aligned) ----
    size_t off = 0;
    unsigned int* ea_h = (unsigned int*)d_ws;   off += (size_t)NE * 8;     // 51.2 MB
    unsigned int* sdp = (unsigned int*)((float*)d_ws + off); off += NE;    // 6.4 MB
    float* abuf = (float*)d_ws + off;          off += (size_t)NN * H;
    float* bbuf = (float*)d_ws + off;          off += (size_t)NN * H;
    float* h_a  = (float*)d_ws + off;          off += (size_t)NN * H;
    float* h_b  = (float*)d_ws + off;          off += (size_t)NN * H;
    float4* xp_a = (float4*)((float*)d_ws + off); off += (size_t)NN * 4;
    float4* xp_b = (float4*)((float*)d_ws + off); off += (size_t)NN * 4;
    float* agg  = (float*)d_ws + off;          off += (size_t)NN * H;      // zeroed once; node re-zeros
    float* dxb  = (float*)d_ws + off;          off += (size_t)NN * 4;      // adjacent to agg
    unsigned int* w1h  = (unsigned int*)((float*)d_ws + off); off += (size_t)NL * 256;
    unsigned int* w2xh = (unsigned int*)((float*)d_ws + off); off += (size_t)NL * 512;
    float* cvec = (float*)d_ws + off;          off += (size_t)NL * H;
    int*   cnt  = (int*)((float*)d_ws + off);  off += (size_t)NN * CPAD;
    int*   rs   = (int*)((float*)d_ws + off);  off += NN + 4;
    int*   rank = (int*)((float*)d_ws + off);  off += NE;

    dim3 nblk((NN + 255) / 256), eblk(NE / 256);   // NE = 6250*256 exactly

    hipMemsetAsync(cnt, 0, (size_t)NN * CPAD * sizeof(int), stream);
    hipMemsetAsync(agg, 0, (size_t)NN * (H + 4) * sizeof(float), stream);  // agg+dxb once
    k_hist<<<eblk, 256, 0, stream>>>(edst, cnt, rank);
    k_scan<<<1, 1024, 0, stream>>>(cnt, rs);
    k_scatter2<<<eblk, 256, 0, stream>>>(esrc, edst, rank, rs, edge_attr, ea_h, sdp);
    k_prep<<<dim3(NL), 256, 0, stream>>>(pe_w1, pe_w2, pe_b2, px_w1, px_b1, w1h, w2xh, cvec);

    proj2<<<nblk, 256, 0, stream>>>(node_feat, node_pos, proj_w, proj_b, pe_w1,
                                    h_a, abuf, bbuf, xp_a);

    const float* hcur = h_a;
    const float4* xcur = xp_a;
    float* hbufs[2] = { h_b, h_a };
    float4* xbufs[2] = { xp_b, xp_a };

    for (int l = 0; l < NL; ++l) {
        egnn_edge6<<<eblk, 256, 0, stream>>>(abuf, bbuf, xcur, ea_h, sdp,
            w1h + (size_t)l * 256, pe_b1 + l * H,
            pe_w1 + (size_t)l * W1ROWS * H,
            w2xh + (size_t)l * 512, cvec + l * H,
            px_w2 + (size_t)l * H,  px_b2 + l,
            agg, dxb);
        int last = (l == NL - 1);
        float* ho = last ? out_h : hbufs[l & 1];
        float* xo = last ? out_x : (float*)xbufs[l & 1];
        const float* nxtw1 = last ? pe_w1 : (pe_w1 + (size_t)(l + 1) * W1ROWS * H);
        egnn_node6<<<nblk, 256, 0, stream>>>(hcur, agg, xcur, dxb, rs,
            pe_w2 + (size_t)l * H * H, pe_b2 + l * H,
            ph_w1 + (size_t)l * 2 * H * H, ph_b1 + l * H,
            ph_w2 + (size_t)l * H * H,     ph_b2 + l * H,
            ln_g + l * H, ln_b + l * H,
            nxtw1, last, ho, xo, abuf, bbuf);
        hcur = ho;
        xcur = xbufs[l & 1];
    }
}

// Round 12
// 959.641 us; speedup vs baseline: 1.2092x; 1.0476x over previous
//
#include <hip/hip_runtime.h>
#include <hip/hip_fp16.h>
#include <math.h>

#define NN 50000
#define NE 1600000
#define H  32
#define ED 16
#define FIN 23
#define NL 4
#define W1ROWS 81   // 2H+ED+1
#define CPAD 16     // ints per histogram counter (64B line)
#define LW 19       // LDS row words: 16 half2-packed m + 3 fp32 coord
#define NBLK 196    // (NN+255)/256

typedef _Float16 hv2 __attribute__((ext_vector_type(2)));
typedef __fp16   fv2 __attribute__((ext_vector_type(2)));
union H2U { unsigned int u; hv2 h; fv2 f; };
union F4 { float4 v; float f[4]; };

__device__ __forceinline__ unsigned int pack2(float a, float b) {
    H2U r; r.f = __builtin_amdgcn_cvt_pkrtz(a, b);
    return r.u;
}

__device__ __forceinline__ float fdot2f(unsigned int a, unsigned int b, float c) {
    H2U ua, ub; ua.u = a; ub.u = b;
    return __builtin_amdgcn_fdot2(ua.h, ub.h, c, false);
}

__device__ __forceinline__ float silu_f(float v) {
    float e = __expf(-v);
    return v * __builtin_amdgcn_rcpf(1.0f + e);
}

// hid += (4 rows of W) dot (4 vals); W rows wave-uniform -> s_load + v_fmac
__device__ __forceinline__ void acc4(float hid[H], float4 hv4, const float* __restrict__ w) {
    F4 u; u.v = hv4;
    #pragma unroll
    for (int jj = 0; jj < 4; ++jj) {
        float v = u.f[jj];
        #pragma unroll
        for (int k = 0; k < H; ++k) hid[k] = fmaf(v, w[jj * H + k], hid[k]);
    }
}

// ---------------- per-layer weight prep: fp16-packed W1e, W2X=W2@XW1, cvec -------

__global__ __launch_bounds__(256) void k_prep(
    const float* __restrict__ pe_w1, const float* __restrict__ pe_w2,
    const float* __restrict__ pe_b2,
    const float* __restrict__ px_w1, const float* __restrict__ px_b1,
    unsigned int* __restrict__ w1h, unsigned int* __restrict__ w2xh,
    float* __restrict__ cvec)
{
    __shared__ float w2x[H * H];
    int l = blockIdx.x;
    const float* w2  = pe_w2 + (size_t)l * H * H;
    const float* xw1 = px_w1 + (size_t)l * H * H;
    int tid = threadIdx.x;
    #pragma unroll
    for (int q = 0; q < 4; ++q) {
        int idx = q * 256 + tid;          // j*32+k
        int j = idx >> 5, k = idx & 31;
        float acc = 0.0f;
        #pragma unroll
        for (int t = 0; t < H; ++t) acc = fmaf(w2[j * H + t], xw1[t * H + k], acc);
        w2x[idx] = acc;
    }
    __syncthreads();
    #pragma unroll
    for (int q = 0; q < 2; ++q) {
        int i2 = q * 256 + tid;           // j2*32+k, j2 in [0,16)
        int j2 = i2 >> 5, k = i2 & 31;
        w2xh[(size_t)l * 512 + i2] = pack2(w2x[(2*j2) * H + k], w2x[(2*j2+1) * H + k]);
    }
    {
        int j2 = tid >> 5, k = tid & 31;  // j2 in [0,8)
        const float* w1 = pe_w1 + (size_t)l * W1ROWS * H;
        w1h[(size_t)l * 256 + tid] = pack2(w1[(2*H + 2*j2) * H + k], w1[(2*H + 2*j2+1) * H + k]);
    }
    if (tid < H) {
        float acc = px_b1[l * H + tid];
        const float* b2 = pe_b2 + l * H;
        #pragma unroll
        for (int t = 0; t < H; ++t) acc = fmaf(b2[t], xw1[t * H + tid], acc);
        cvec[l * H + tid] = acc;
    }
}

// ---------------- CSR build (once per call) ----------------

// count-only histogram (rank array eliminated; scatter uses cursor atomics)
__global__ __launch_bounds__(256) void k_hist(
    const int* __restrict__ edst, int* __restrict__ cnt)
{
    int e = blockIdx.x * 256 + threadIdx.x;
    if (e >= NE) return;
    atomicAdd(&cnt[(size_t)edst[e] * CPAD], 1);
}

// two-level scan: (a) block-local exclusive scan + block totals
__global__ __launch_bounds__(256) void k_scan_a(
    const int* __restrict__ cnt, int* __restrict__ rs, int* __restrict__ bsum)
{
    __shared__ int ws[4];
    int t = threadIdx.x;
    int lane = t & 63, wv = t >> 6;
    int i = blockIdx.x * 256 + t;
    int v = (i < NN) ? cnt[(size_t)i * CPAD] : 0;
    int incl = v;
    #pragma unroll
    for (int off = 1; off < 64; off <<= 1) {
        int u = __shfl_up(incl, off, 64);
        if (lane >= off) incl += u;
    }
    if (lane == 63) ws[wv] = incl;
    __syncthreads();
    int wpre = 0;
    #pragma unroll
    for (int w = 0; w < 4; ++w) { int s = ws[w]; wpre += (w < wv) ? s : 0; }
    if (i < NN) rs[i] = wpre + incl - v;           // block-local exclusive
    if (t == 255) bsum[blockIdx.x] = wpre + incl;  // block total
}

// (b) scan of the 196 block totals (single block)
__global__ __launch_bounds__(256) void k_scan_b(
    const int* __restrict__ bsum, int* __restrict__ boff, int* __restrict__ rs)
{
    __shared__ int ws[4];
    int t = threadIdx.x;
    int lane = t & 63, wv = t >> 6;
    int v = (t < NBLK) ? bsum[t] : 0;
    int incl = v;
    #pragma unroll
    for (int off = 1; off < 64; off <<= 1) {
        int u = __shfl_up(incl, off, 64);
        if (lane >= off) incl += u;
    }
    if (lane == 63) ws[wv] = incl;
    __syncthreads();
    int wpre = 0;
    #pragma unroll
    for (int w = 0; w < 4; ++w) { int s = ws[w]; wpre += (w < wv) ? s : 0; }
    if (t < NBLK) boff[t] = wpre + incl - v;
    if (t == 255) rs[NN] = wpre + incl;            // = NE
}

// (c) add block offsets; init cursor = rs
__global__ __launch_bounds__(256) void k_scan_c(
    int* __restrict__ rs, const int* __restrict__ boff, int* __restrict__ cursor)
{
    int i = blockIdx.x * 256 + threadIdx.x;
    if (i >= NN) return;
    int r = rs[i] + boff[blockIdx.x];
    rs[i] = r;
    cursor[i] = r;
}

// scatter+permute via cursor atomic: fp16-convert edge_attr + pack (src,dst) at slot
__global__ __launch_bounds__(256) void k_scatter3(
    const int* __restrict__ esrc, const int* __restrict__ edst,
    int* __restrict__ cursor, const float* __restrict__ ea,
    unsigned int* __restrict__ ea_h, unsigned int* __restrict__ sdp)
{
    int e = blockIdx.x * 256 + threadIdx.x;
    if (e >= NE) return;
    int s = esrc[e], d = edst[e];
    int slot = atomicAdd(&cursor[d], 1);
    const float4* src4 = (const float4*)(ea + (size_t)e * ED);   // coalesced read
    uint2* dst2 = (uint2*)(ea_h + (size_t)slot * 8);             // random 32B write
    #pragma unroll
    for (int j = 0; j < ED / 4; ++j) {
        float4 v = src4[j];
        uint2 o; o.x = pack2(v.x, v.y); o.y = pack2(v.z, v.w);
        dst2[j] = o;
    }
    sdp[slot] = (unsigned int)s | ((unsigned int)d << 16);       // both < 2^16
}

// ---------------- input projection + x padding + layer-0 a/b (b1 folded into a) --

__global__ __launch_bounds__(256) void proj2(
    const float* __restrict__ feat, const float* __restrict__ pos,
    const float* __restrict__ W, const float* __restrict__ bias,
    const float* __restrict__ pew1, const float* __restrict__ eb1,
    float* __restrict__ h, float* __restrict__ a, float* __restrict__ b,
    float4* __restrict__ xp)
{
    int n = blockIdx.x * 256 + threadIdx.x;
    if (n >= NN) return;
    float acc[H];
    #pragma unroll
    for (int k = 0; k < H; ++k) acc[k] = bias[k];
    #pragma unroll 1
    for (int j = 0; j < FIN; ++j) {
        float v = feat[n * FIN + j];
        const float* w = W + j * H;
        #pragma unroll
        for (int k = 0; k < H; ++k) acc[k] = fmaf(v, w[k], acc[k]);
    }
    float4* h4 = (float4*)(h + (size_t)n * H);
    #pragma unroll
    for (int k4 = 0; k4 < H / 4; ++k4) {
        float4 o;
        o.x = acc[4*k4+0]; o.y = acc[4*k4+1]; o.z = acc[4*k4+2]; o.w = acc[4*k4+3];
        h4[k4] = o;
    }
    float pa[H];
    #pragma unroll
    for (int k = 0; k < H; ++k) pa[k] = eb1[k];     // b1 folded into a-projection
    #pragma unroll 1
    for (int j = 0; j < H; ++j) {
        float v = acc[j];
        const float* w = pew1 + j * H;
        #pragma unroll
        for (int k = 0; k < H; ++k) pa[k] = fmaf(v, w[k], pa[k]);
    }
    float4* a4 = (float4*)(a + (size_t)n * H);
    #pragma unroll
    for (int k4 = 0; k4 < H / 4; ++k4) {
        float4 o;
        o.x = pa[4*k4+0]; o.y = pa[4*k4+1]; o.z = pa[4*k4+2]; o.w = pa[4*k4+3];
        a4[k4] = o;
    }
    #pragma unroll
    for (int k = 0; k < H; ++k) pa[k] = 0.0f;
    #pragma unroll 1
    for (int j = 0; j < H; ++j) {
        float v = acc[j];
        const float* w = pew1 + (H + j) * H;
        #pragma unroll
        for (int k = 0; k < H; ++k) pa[k] = fmaf(v, w[k], pa[k]);
    }
    float4* b4 = (float4*)(b + (size_t)n * H);
    #pragma unroll
    for (int k4 = 0; k4 < H / 4; ++k4) {
        float4 o;
        o.x = pa[4*k4+0]; o.y = pa[4*k4+1]; o.z = pa[4*k4+2]; o.w = pa[4*k4+3];
        b4[k4] = o;
    }
    float4 xo;
    xo.x = pos[3*n+0]; xo.y = pos[3*n+1]; xo.z = pos[3*n+2]; xo.w = 0.0f;
    xp[n] = xo;
}

// ---------------- edge kernel: fdot2 GEMMs + barrier-free cooperative seg-reduce --

__global__ __launch_bounds__(256) void egnn_edge7(
    const float* __restrict__ a, const float* __restrict__ b,
    const float4* __restrict__ xp,
    const unsigned int* __restrict__ ea_h, const unsigned int* __restrict__ sdp,
    const unsigned int* __restrict__ w1h,
    const float* __restrict__ w1,          // fp32 layer W1 (for dist row 80)
    const unsigned int* __restrict__ w2xh, const float* __restrict__ cvec,
    const float* __restrict__ xw2, const float* __restrict__ xb2,
    float* __restrict__ agg, float* __restrict__ dxb)
{
    __shared__ unsigned int ldsu[256 * LW + 4];   // +4: c==3 dummy-read pad

    int tid = threadIdx.x;
    int w = tid >> 6, lane = tid & 63;
    int slot = blockIdx.x * 256 + tid;            // grid exact: NE = 6250*256

    unsigned int sd = sdp[slot];
    int s = (int)(sd & 0xffffu), d = (int)(sd >> 16);

    // hid = a[src] + b[dst]   (b1 pre-folded into a)
    float hid[H];
    const float4* av = (const float4*)(a + (size_t)s * H);
    const float4* bv = (const float4*)(b + (size_t)d * H);
    #pragma unroll
    for (int k4 = 0; k4 < H / 4; ++k4) {
        F4 ua, ub; ua.v = av[k4]; ub.v = bv[k4];
        #pragma unroll
        for (int jj = 0; jj < 4; ++jj)
            hid[4*k4+jj] = ua.f[jj] + ub.f[jj];
    }

    // + ea(fp16) @ W1e(fp16) via dot2
    const uint4* ev = (const uint4*)(ea_h + (size_t)slot * 8);
    uint4 e0 = ev[0], e1 = ev[1];
    unsigned int ew[8] = { e0.x, e0.y, e0.z, e0.w, e1.x, e1.y, e1.z, e1.w };
    #pragma unroll 1
    for (int j2 = 0; j2 < 8; ++j2) {
        unsigned int ea2 = ew[j2];
        const unsigned int* wr = w1h + j2 * H;
        #pragma unroll
        for (int k = 0; k < H; ++k) hid[k] = fdot2f(ea2, wr[k], hid[k]);
    }

    // + dist * W1[row 80] (fp32)
    float4 xi = xp[s];
    float4 xj = xp[d];
    float d0 = xj.x - xi.x, d1 = xj.y - xi.y, d2 = xj.z - xi.z;
    float sq = d0*d0 + d1*d1 + d2*d2;
    float dist = __builtin_amdgcn_sqrtf(sq + 1e-9f);
    {
        const float* wl = w1 + (2 * H + ED) * H;
        #pragma unroll
        for (int k = 0; k < H; ++k) hid[k] = fmaf(dist, wl[k], hid[k]);
    }

    // s = silu(hid) packed fp16 pairs (reused for GEMM2 AND the LDS row)
    unsigned int sp[16];
    #pragma unroll
    for (int j2 = 0; j2 < 16; ++j2)
        sp[j2] = pack2(silu_f(hid[2*j2]), silu_f(hid[2*j2+1]));

    // gh = cvec + s @ W2X via dot2
    float gh[H];
    #pragma unroll
    for (int k = 0; k < H; ++k) gh[k] = cvec[k];
    #pragma unroll 1
    for (int j2 = 0; j2 < 16; ++j2) {
        unsigned int sv = sp[j2];
        const unsigned int* wr = w2xh + j2 * H;
        #pragma unroll
        for (int k = 0; k < H; ++k) gh[k] = fdot2f(sv, wr[k], gh[k]);
    }

    float gate = xb2[0];
    #pragma unroll
    for (int j = 0; j < H; ++j) gate = fmaf(silu_f(gh[j]), xw2[j], gate);
    float scale = gate * __builtin_amdgcn_rcpf(__builtin_amdgcn_sqrtf(sq) + 1e-9f);

    // stash row: 16 packed m words + 3 fp32 coord words
    unsigned int* row = &ldsu[tid * LW];
    #pragma unroll
    for (int k2 = 0; k2 < 16; ++k2) row[k2] = sp[k2];
    row[16] = __float_as_uint(d0 * scale);
    row[17] = __float_as_uint(d1 * scale);
    row[18] = __float_as_uint(d2 * scale);

    // wave-local segments (dst-sorted slots); NO __syncthreads needed:
    // each wave reads only its own 64 LDS rows.
    int dprev = __shfl_up(d, 1, 64);
    bool flag = (lane == 0) || (d != dprev);
    unsigned long long ball = __ballot(flag);

    int half = lane >> 5, col = lane & 31;
    int word = col >> 1, sh = (col & 1) * 16;
    int c = lane & 3, strip = lane >> 2;
    const unsigned int* wrows = &ldsu[(w * 64) * LW];

    unsigned long long cur = ball;
    while (cur) {
        int r0 = (int)__builtin_ctzll(cur);
        unsigned long long nxt = cur & (cur - 1);
        int r1 = nxt ? (int)__builtin_ctzll(nxt) : 64;
        int dseg = __shfl(d, r0, 64);

        // m columns: 64 lanes = 32 cols x 2 row-strips
        float v = 0.0f;
        #pragma unroll 1
        for (int r = r0 + half; r < r1; r += 2) {
            unsigned int u = wrows[r * LW + word];
            v += __half2float(__ushort_as_half((unsigned short)(u >> sh)));
        }
        v += __shfl_xor(v, 32, 64);
        if (lane < 32) unsafeAtomicAdd(&agg[(size_t)dseg * H + col], v);

        // coord columns: 4 "cols" (3 real) x 16 row-strips
        float cv = 0.0f;
        #pragma unroll 1
        for (int r = r0 + strip; r < r1; r += 16)
            cv += __uint_as_float(wrows[r * LW + 16 + c]);
        cv += __shfl_xor(cv, 4, 64);
        cv += __shfl_xor(cv, 8, 64);
        cv += __shfl_xor(cv, 16, 64);
        cv += __shfl_xor(cv, 32, 64);
        if (lane < 3) unsafeAtomicAdd(&dxb[(size_t)dseg * 4 + c], cv);

        cur = nxt;
    }
}

// ---------------- node kernel: finish agg, phi_h, LN, x, next a/b; re-zero agg ---

__global__ __launch_bounds__(256) void egnn_node7(
    const float* __restrict__ h, float* __restrict__ agg,
    const float4* __restrict__ xin, float* __restrict__ dxb,
    const int* __restrict__ rs,
    const float* __restrict__ ew2, const float* __restrict__ eb2,
    const float* __restrict__ w1, const float* __restrict__ b1,
    const float* __restrict__ w2, const float* __restrict__ b2,
    const float* __restrict__ lng, const float* __restrict__ lnb,
    const float* __restrict__ nxtw1, const float* __restrict__ nxtb1, int last,
    float* __restrict__ hout, float* __restrict__ xout,
    float* __restrict__ aout, float* __restrict__ bout)
{
    int n = blockIdx.x * 256 + threadIdx.x;
    if (n >= NN) return;
    const float4* h4 = (const float4*)(h + (size_t)n * H);
    float4* a4 = (float4*)(agg + (size_t)n * H);

    // ma = deg*b2_e + agg_s @ W2_e
    float degf = (float)(rs[n + 1] - rs[n]);
    float ma[H];
    #pragma unroll
    for (int k = 0; k < H; ++k) ma[k] = degf * eb2[k];
    #pragma unroll 1
    for (int j4 = 0; j4 < H / 4; ++j4)
        acc4(ma, a4[j4], ew2 + (j4 * 4) * H);

    // re-zero agg for next layer's edge atomics (replaces per-layer memset)
    float4 z; z.x = 0.0f; z.y = 0.0f; z.z = 0.0f; z.w = 0.0f;
    #pragma unroll
    for (int j4 = 0; j4 < H / 4; ++j4) a4[j4] = z;

    float hv[H];
    float hid[H];
    #pragma unroll
    for (int k = 0; k < H; ++k) hid[k] = b1[k];
    #pragma unroll 1
    for (int j4 = 0; j4 < H / 4; ++j4) {
        F4 u; u.v = h4[j4];
        #pragma unroll
        for (int jj = 0; jj < 4; ++jj) hv[4*j4+jj] = u.f[jj];
        acc4(hid, u.v, w1 + (j4 * 4) * H);
    }
    #pragma unroll
    for (int j = 0; j < H; ++j) {
        float v = ma[j];
        const float* ww = w1 + (H + j) * H;
        #pragma unroll
        for (int k = 0; k < H; ++k) hid[k] = fmaf(v, ww[k], hid[k]);
    }

    float dh[H];
    #pragma unroll
    for (int k = 0; k < H; ++k) dh[k] = b2[k];
    #pragma unroll
    for (int j = 0; j < H; ++j) {
        float v = silu_f(hid[j]);
        const float* ww = w2 + j * H;
        #pragma unroll
        for (int k = 0; k < H; ++k) dh[k] = fmaf(v, ww[k], dh[k]);
    }

    float y[H];
    float mu = 0.0f;
    #pragma unroll
    for (int k = 0; k < H; ++k) { y[k] = hv[k] + dh[k]; mu += y[k]; }
    mu *= (1.0f / H);
    float var = 0.0f;
    #pragma unroll
    for (int k = 0; k < H; ++k) { float t = y[k] - mu; var += t * t; }
    var *= (1.0f / H);
    float rstd = rsqrtf(var + 1e-5f);

    float hn[H];
    #pragma unroll
    for (int k = 0; k < H; ++k) hn[k] = (y[k] - mu) * rstd * lng[k] + lnb[k];

    float4* ho4 = (float4*)(hout + (size_t)n * H);
    #pragma unroll
    for (int k4 = 0; k4 < H / 4; ++k4) {
        float4 o;
        o.x = hn[4*k4+0]; o.y = hn[4*k4+1]; o.z = hn[4*k4+2]; o.w = hn[4*k4+3];
        ho4[k4] = o;
    }

    float4 xi = xin[n];
    float nx0 = xi.x + dxb[(size_t)n * 4 + 0];
    float nx1 = xi.y + dxb[(size_t)n * 4 + 1];
    float nx2 = xi.z + dxb[(size_t)n * 4 + 2];
    ((float4*)dxb)[n] = z;   // re-zero for next layer
    if (last) {
        xout[3*n+0] = nx0; xout[3*n+1] = nx1; xout[3*n+2] = nx2;
    } else {
        float4 o; o.x = nx0; o.y = nx1; o.z = nx2; o.w = 0.0f;
        ((float4*)xout)[n] = o;
    }

    if (!last) {
        float pa[H];
        #pragma unroll
        for (int k = 0; k < H; ++k) pa[k] = nxtb1[k];   // fold next layer's b1
        #pragma unroll 1
        for (int j = 0; j < H; ++j) {
            float v = hn[j];
            const float* ww = nxtw1 + j * H;
            #pragma unroll
            for (int k = 0; k < H; ++k) pa[k] = fmaf(v, ww[k], pa[k]);
        }
        float4* ao4 = (float4*)(aout + (size_t)n * H);
        #pragma unroll
        for (int k4 = 0; k4 < H / 4; ++k4) {
            float4 o;
            o.x = pa[4*k4+0]; o.y = pa[4*k4+1]; o.z = pa[4*k4+2]; o.w = pa[4*k4+3];
            ao4[k4] = o;
        }
        #pragma unroll
        for (int k = 0; k < H; ++k) pa[k] = 0.0f;
        #pragma unroll 1
        for (int j = 0; j < H; ++j) {
            float v = hn[j];
            const float* ww = nxtw1 + (H + j) * H;
            #pragma unroll
            for (int k = 0; k < H; ++k) pa[k] = fmaf(v, ww[k], pa[k]);
        }
        float4* bo4 = (float4*)(bout + (size_t)n * H);
        #pragma unroll
        for (int k4 = 0; k4 < H / 4; ++k4) {
            float4 o;
            o.x = pa[4*k4+0]; o.y = pa[4*k4+1]; o.z = pa[4*k4+2]; o.w = pa[4*k4+3];
            bo4[k4] = o;
        }
    }
}

extern "C" void kernel_launch(void* const* d_in, const int* in_sizes, int n_in,
                              void* d_out, int out_size, void* d_ws, size_t ws_size,
                              hipStream_t stream) {
    const float* node_pos  = (const float*)d_in[0];
    const float* node_feat = (const float*)d_in[1];
    const float* edge_attr = (const float*)d_in[2];
    const float* proj_w    = (const float*)d_in[3];
    const float* proj_b    = (const float*)d_in[4];
    const float* pe_w1     = (const float*)d_in[5];
    const float* pe_b1     = (const float*)d_in[6];
    const float* pe_w2     = (const float*)d_in[7];
    const float* pe_b2     = (const float*)d_in[8];
    const float* ph_w1     = (const float*)d_in[9];
    const float* ph_b1     = (const float*)d_in[10];
    const float* ph_w2     = (const float*)d_in[11];
    const float* ph_b2     = (const float*)d_in[12];
    const float* px_w1     = (const float*)d_in[13];
    const float* px_b1     = (const float*)d_in[14];
    const float* px_w2     = (const float*)d_in[15];
    const float* px_b2     = (const float*)d_in[16];
    const float* ln_g      = (const float*)d_in[17];
    const float* ln_b      = (const float*)d_in[18];
    const int*   eidx      = (const int*)d_in[19];
    const int*   esrc      = eidx;
    const int*   edst      = eidx + NE;

    float* out_h = (float*)d_out;
    float* out_x = out_h + (size_t)NN * H;

    // ---- workspace layout (offsets in 4B words; all 16B aligned) ----
    size_t off = 0;
    unsigned int* ea_h = (unsigned int*)d_ws;   off += (size_t)NE * 8;     // 51.2 MB
    unsigned int* sdp = (unsigned int*)((float*)d_ws + off); off += NE;    // 6.4 MB
    float* abuf = (float*)d_ws + off;          off += (size_t)NN * H;
    float* bbuf = (float*)d_ws + off;          off += (size_t)NN * H;
    float* h_a  = (float*)d_ws + off;          off += (size_t)NN * H;
    float* h_b  = (float*)d_ws + off;          off += (size_t)NN * H;
    float4* xp_a = (float4*)((float*)d_ws + off); off += (size_t)NN * 4;
    float4* xp_b = (float4*)((float*)d_ws + off); off += (size_t)NN * 4;
    float* agg  = (float*)d_ws + off;          off += (size_t)NN * H;      // zeroed once; node re-zeros
    float* dxb  = (float*)d_ws + off;          off += (size_t)NN * 4;      // adjacent to agg
    unsigned int* w1h  = (unsigned int*)((float*)d_ws + off); off += (size_t)NL * 256;
    unsigned int* w2xh = (unsigned int*)((float*)d_ws + off); off += (size_t)NL * 512;
    float* cvec = (float*)d_ws + off;          off += (size_t)NL * H;
    int*   cnt  = (int*)((float*)d_ws + off);  off += (size_t)NN * CPAD;
    int*   rs   = (int*)((float*)d_ws + off);  off += NN + 4;
    int*   cursor = (int*)((float*)d_ws + off); off += NN;
    int*   bsum = (int*)((float*)d_ws + off);  off += 256;
    int*   boff = (int*)((float*)d_ws + off);  off += 256;

    dim3 nblk(NBLK), eblk(NE / 256);   // NE = 6250*256 exactly

    hipMemsetAsync(cnt, 0, (size_t)NN * CPAD * sizeof(int), stream);
    hipMemsetAsync(agg, 0, (size_t)NN * (H + 4) * sizeof(float), stream);  // agg+dxb once
    k_hist<<<eblk, 256, 0, stream>>>(edst, cnt);
    k_scan_a<<<nblk, 256, 0, stream>>>(cnt, rs, bsum);
    k_scan_b<<<1, 256, 0, stream>>>(bsum, boff, rs);
    k_scan_c<<<nblk, 256, 0, stream>>>(rs, boff, cursor);
    k_scatter3<<<eblk, 256, 0, stream>>>(esrc, edst, cursor, edge_attr, ea_h, sdp);
    k_prep<<<dim3(NL), 256, 0, stream>>>(pe_w1, pe_w2, pe_b2, px_w1, px_b1, w1h, w2xh, cvec);

    proj2<<<nblk, 256, 0, stream>>>(node_feat, node_pos, proj_w, proj_b, pe_w1, pe_b1,
                                    h_a, abuf, bbuf, xp_a);

    const float* hcur = h_a;
    const float4* xcur = xp_a;
    float* hbufs[2] = { h_b, h_a };
    float4* xbufs[2] = { xp_b, xp_a };

    for (int l = 0; l < NL; ++l) {
        egnn_edge7<<<eblk, 256, 0, stream>>>(abuf, bbuf, xcur, ea_h, sdp,
            w1h + (size_t)l * 256,
            pe_w1 + (size_t)l * W1ROWS * H,
            w2xh + (size_t)l * 512, cvec + l * H,
            px_w2 + (size_t)l * H,  px_b2 + l,
            agg, dxb);
        int last = (l == NL - 1);
        float* ho = last ? out_h : hbufs[l & 1];
        float* xo = last ? out_x : (float*)xbufs[l & 1];
        const float* nxtw1 = last ? pe_w1 : (pe_w1 + (size_t)(l + 1) * W1ROWS * H);
        const float* nxtb1 = last ? pe_b1 : (pe_b1 + (l + 1) * H);
        egnn_node7<<<nblk, 256, 0, stream>>>(hcur, agg, xcur, dxb, rs,
            pe_w2 + (size_t)l * H * H, pe_b2 + l * H,
            ph_w1 + (size_t)l * 2 * H * H, ph_b1 + l * H,
            ph_w2 + (size_t)l * H * H,     ph_b2 + l * H,
            ln_g + l * H, ln_b + l * H,
            nxtw1, nxtb1, last, ho, xo, abuf, bbuf);
        hcur = ho;
        xcur = xbufs[l & 1];
    }
}